// Round 1
// baseline (371.114 us; speedup 1.0000x reference)
//
#include <hip/hip_runtime.h>

// MHA: out = softmax_causal((XWq)(XWk)^T / 8) (XWv) Wo
// B=2 S=2048 DM=1024 H=16 d=64. Inputs fp32, output fp32, bf16 MFMA compute.

typedef __attribute__((ext_vector_type(8))) short v8s;   // 8 x bf16 (4 VGPRs)
typedef __attribute__((ext_vector_type(4))) float v4f;   // MFMA accumulator

#define MFMA16(a, b, c) __builtin_amdgcn_mfma_f32_16x16x32_bf16(a, b, c, 0, 0, 0)

__device__ __forceinline__ short f2bf(float f) {
  union { float f; unsigned u; } x; x.f = f;
  unsigned r = x.u + 0x7fffu + ((x.u >> 16) & 1u);  // RNE
  return (short)(r >> 16);
}
__device__ __forceinline__ float bf2f(short s) {
  union { unsigned u; float f; } x; x.u = ((unsigned)(unsigned short)s) << 16;
  return x.f;
}

// ---------------------------------------------------------------------------
// Weight transpose+cast: W[1024][1024] f32 (row-major [k][n]) -> Wt[n][k] bf16
// ---------------------------------------------------------------------------
__global__ __launch_bounds__(256) void wtrans_kernel(const float* __restrict__ W,
                                                     short* __restrict__ Wt) {
  __shared__ __align__(16) short tile[64 * 72];  // [n][k], stride 72 breaks conflicts
  const int NN = 1024;
  int n0 = blockIdx.x * 64, k0 = blockIdx.y * 64;
  int t = threadIdx.x;
  int r = t >> 4;         // k row within tile (step 16)
  int c4 = (t & 15) * 4;  // n within tile
  for (int rr = r; rr < 64; rr += 16) {
    float4 f = *(const float4*)(W + (size_t)(k0 + rr) * NN + n0 + c4);
    tile[(c4 + 0) * 72 + rr] = f2bf(f.x);
    tile[(c4 + 1) * 72 + rr] = f2bf(f.y);
    tile[(c4 + 2) * 72 + rr] = f2bf(f.z);
    tile[(c4 + 3) * 72 + rr] = f2bf(f.w);
  }
  __syncthreads();
  int nr = t >> 2, kc = (t & 3) * 16;
  v8s v0 = *(const v8s*)&tile[nr * 72 + kc];
  v8s v1 = *(const v8s*)&tile[nr * 72 + kc + 8];
  *(v8s*)(Wt + (size_t)(n0 + nr) * NN + k0 + kc) = v0;
  *(v8s*)(Wt + (size_t)(n0 + nr) * NN + k0 + kc + 8) = v1;
}

// ---------------------------------------------------------------------------
// GEMM: C[M][N] = A[M][K] * Bt[N][K]^T.  A fp32 (cast on stage) or bf16.
// 128x128 tile, BK=32, 4 waves each 64x64 (4x4 fragments of 16x16x32 MFMA).
// ---------------------------------------------------------------------------
template <bool A_F32, bool OUT_F32>
__global__ __launch_bounds__(256) void gemm_bt_kernel(const void* __restrict__ Aptr,
                                                      const short* __restrict__ Bt,
                                                      void* __restrict__ Cptr,
                                                      int M, int N, int K) {
  __shared__ __align__(16) short As[128 * 40];  // [m][k] stride 40
  __shared__ __align__(16) short Bs[128 * 40];  // [n][k] stride 40
  int row0 = blockIdx.y * 128, col0 = blockIdx.x * 128;
  int t = threadIdx.x;
  int lane = t & 63, w = t >> 6;
  int wm = (w >> 1) * 64, wn = (w & 1) * 64;
  int lr = lane & 15, lg = lane >> 4;

  v4f acc[4][4];
  for (int i = 0; i < 4; ++i)
    for (int j = 0; j < 4; ++j) acc[i][j] = {0.f, 0.f, 0.f, 0.f};

  for (int k0 = 0; k0 < K; k0 += 32) {
    __syncthreads();  // protect LDS vs previous iteration's reads
    for (int c = t; c < 512; c += 256) {   // 512 chunks of 8 bf16 per operand
      int row = c >> 2, kc = (c & 3) * 8;
      v8s av;
      if (A_F32) {
        const float* A = (const float*)Aptr;
        float4 f0 = *(const float4*)(A + (size_t)(row0 + row) * K + k0 + kc);
        float4 f1 = *(const float4*)(A + (size_t)(row0 + row) * K + k0 + kc + 4);
        av[0] = f2bf(f0.x); av[1] = f2bf(f0.y); av[2] = f2bf(f0.z); av[3] = f2bf(f0.w);
        av[4] = f2bf(f1.x); av[5] = f2bf(f1.y); av[6] = f2bf(f1.z); av[7] = f2bf(f1.w);
      } else {
        av = *(const v8s*)((const short*)Aptr + (size_t)(row0 + row) * K + k0 + kc);
      }
      *(v8s*)&As[row * 40 + kc] = av;
      v8s bv = *(const v8s*)(Bt + (size_t)(col0 + row) * K + k0 + kc);
      *(v8s*)&Bs[row * 40 + kc] = bv;
    }
    __syncthreads();
    v8s af[4], bg[4];
    for (int mf = 0; mf < 4; ++mf)
      af[mf] = *(const v8s*)&As[(wm + mf * 16 + lr) * 40 + lg * 8];
    for (int nf = 0; nf < 4; ++nf)
      bg[nf] = *(const v8s*)&Bs[(wn + nf * 16 + lr) * 40 + lg * 8];
    for (int mf = 0; mf < 4; ++mf)
      for (int nf = 0; nf < 4; ++nf)
        acc[mf][nf] = MFMA16(af[mf], bg[nf], acc[mf][nf]);
  }

  // C layout: col = lane&15, row = (lane>>4)*4 + reg  [m89-verified]
  for (int mf = 0; mf < 4; ++mf)
    for (int nf = 0; nf < 4; ++nf)
      for (int r = 0; r < 4; ++r) {
        int row = row0 + wm + mf * 16 + lg * 4 + r;
        int col = col0 + wn + nf * 16 + lr;
        if (OUT_F32)
          ((float*)Cptr)[(size_t)row * N + col] = acc[mf][nf][r];
        else
          ((short*)Cptr)[(size_t)row * N + col] = f2bf(acc[mf][nf][r]);
      }
}

// ---------------------------------------------------------------------------
// Causal flash attention. Q/K/V bf16 [B*S][1024] ([s][h*64+d]); ctx same layout.
// Block = (qt, b*16+h): 64 q-rows, 4 waves x 16 rows. KT=32 keys/iter.
// ---------------------------------------------------------------------------
__global__ __launch_bounds__(256) void attn_kernel(const short* __restrict__ Qm,
                                                   const short* __restrict__ Km,
                                                   const short* __restrict__ Vm,
                                                   short* __restrict__ Cm) {
  const int S = 2048, DM = 1024;
  __shared__ __align__(16) short Ks[32 * 72];   // [k][d] stride 72
  __shared__ __align__(16) short Vt[64 * 40];   // [d][k] stride 40 (transposed)
  __shared__ __align__(16) short Ps[4][16 * 40];  // per-wave P [q][k] stride 40
  int qt = blockIdx.x;  // 0..31
  int bh = blockIdx.y;  // 0..31
  int b = bh >> 4, h = bh & 15;
  int t = threadIdx.x;
  int lane = t & 63, w = t >> 6;
  int lr = lane & 15, lg = lane >> 4;
  size_t base = (size_t)b * S * DM + h * 64;
  int qbase = qt * 64 + w * 16;

  // Q fragments (16 rows x 64 d), hoisted
  const short* Qp = Qm + base + (size_t)(qbase + lr) * DM + lg * 8;
  v8s qf0 = *(const v8s*)Qp;
  v8s qf1 = *(const v8s*)(Qp + 32);

  float mrow[4], ssum[4];
  v4f o[4];
  for (int r = 0; r < 4; ++r) { mrow[r] = -1e30f; ssum[r] = 0.f; }
  for (int d = 0; d < 4; ++d) o[d] = {0.f, 0.f, 0.f, 0.f};

  int srow = t >> 3;        // 0..31 (k row staged by this thread)
  int sc8 = (t & 7) * 8;    // d chunk
  int nkt = 2 * qt + 2;     // K tiles covering [0, qt*64+64)

  for (int kt = 0; kt < nkt; ++kt) {
    int k0 = kt * 32;
    __syncthreads();
    {  // stage K row-major, V transposed
      const short* Kg = Km + base + (size_t)(k0 + srow) * DM + sc8;
      v8s kv = *(const v8s*)Kg;
      *(v8s*)&Ks[srow * 72 + sc8] = kv;
      const short* Vg = Vm + base + (size_t)(k0 + srow) * DM + sc8;
      v8s vv = *(const v8s*)Vg;
      for (int jj = 0; jj < 8; ++jj) {
        int j = (jj + t) & 7;  // stagger to spread banks
        Vt[(sc8 + j) * 40 + srow] = vv[j];
      }
    }
    __syncthreads();

    // S = Q K^T : two 16x16 k-fragments, 2 MFMAs each (d = 0:32, 32:64)
    v4f sf[2];
    for (int kf = 0; kf < 2; ++kf) {
      v4f s = {0.f, 0.f, 0.f, 0.f};
      v8s b0 = *(const v8s*)&Ks[(kf * 16 + lr) * 72 + lg * 8];
      v8s b1 = *(const v8s*)&Ks[(kf * 16 + lr) * 72 + 32 + lg * 8];
      s = MFMA16(qf0, b0, s);
      s = MFMA16(qf1, b1, s);
      sf[kf] = s;
    }
    // scale + causal mask; row max
    float tm[4];
    for (int r = 0; r < 4; ++r) {
      int qg = qbase + lg * 4 + r;
      float s0 = sf[0][r] * 0.125f;
      float s1 = sf[1][r] * 0.125f;
      if (k0 + lr > qg) s0 = -1e30f;
      if (k0 + 16 + lr > qg) s1 = -1e30f;
      sf[0][r] = s0; sf[1][r] = s1;
      tm[r] = fmaxf(s0, s1);
    }
    for (int off = 1; off < 16; off <<= 1)
      for (int r = 0; r < 4; ++r)
        tm[r] = fmaxf(tm[r], __shfl_xor(tm[r], off, 64));

    // online softmax update; write P (bf16) to wave-private LDS
    float scl[4], ts[4];
    for (int r = 0; r < 4; ++r) {
      float nm = fmaxf(mrow[r], tm[r]);
      scl[r] = __expf(mrow[r] - nm);
      mrow[r] = nm;
      float p0 = __expf(sf[0][r] - nm);
      float p1 = __expf(sf[1][r] - nm);
      short pb0 = f2bf(p0), pb1 = f2bf(p1);
      Ps[w][(lg * 4 + r) * 40 + lr] = pb0;
      Ps[w][(lg * 4 + r) * 40 + 16 + lr] = pb1;
      ts[r] = bf2f(pb0) + bf2f(pb1);  // sum what we actually store
    }
    for (int off = 1; off < 16; off <<= 1)
      for (int r = 0; r < 4; ++r)
        ts[r] += __shfl_xor(ts[r], off, 64);
    for (int r = 0; r < 4; ++r) ssum[r] = ssum[r] * scl[r] + ts[r];
    for (int d = 0; d < 4; ++d)
      for (int r = 0; r < 4; ++r) o[d][r] *= scl[r];

    // PV: P [16q x 32k] as A-frag, V from transposed LDS as B-frags
    v8s pa = *(const v8s*)&Ps[w][lr * 40 + lg * 8];
    for (int d = 0; d < 4; ++d) {
      v8s vf = *(const v8s*)&Vt[(d * 16 + lr) * 40 + lg * 8];
      o[d] = MFMA16(pa, vf, o[d]);
    }
  }

  short* Cp = Cm + base;
  for (int r = 0; r < 4; ++r) {
    float inv = 1.0f / ssum[r];
    for (int d = 0; d < 4; ++d)
      Cp[(size_t)(qbase + lg * 4 + r) * DM + d * 16 + lr] = f2bf(o[d][r] * inv);
  }
}

// ---------------------------------------------------------------------------
extern "C" void kernel_launch(void* const* d_in, const int* in_sizes, int n_in,
                              void* d_out, int out_size, void* d_ws, size_t ws_size,
                              hipStream_t stream) {
  const float* q_in = (const float*)d_in[0];
  const float* k_in = (const float*)d_in[1];
  const float* v_in = (const float*)d_in[2];
  // d_in[3] = mask: causal triu(k=1), applied analytically in attn_kernel
  const float* w_q = (const float*)d_in[4];
  const float* w_k = (const float*)d_in[5];
  const float* w_v = (const float*)d_in[6];
  const float* w_o = (const float*)d_in[7];
  float* outp = (float*)d_out;

  short* ws = (short*)d_ws;
  short* Wtq = ws;                    // 1M bf16 each
  short* Wtk = Wtq + (1u << 20);
  short* Wtv = Wtk + (1u << 20);
  short* Wto = Wtv + (1u << 20);
  short* Qb = Wto + (1u << 20);       // 4M bf16 each
  short* Kb = Qb + (4u << 20);
  short* Vb = Kb + (4u << 20);
  short* Cb = Vb + (4u << 20);        // total 40 MB

  dim3 tb(256);
  wtrans_kernel<<<dim3(16, 16), tb, 0, stream>>>(w_q, Wtq);
  wtrans_kernel<<<dim3(16, 16), tb, 0, stream>>>(w_k, Wtk);
  wtrans_kernel<<<dim3(16, 16), tb, 0, stream>>>(w_v, Wtv);
  wtrans_kernel<<<dim3(16, 16), tb, 0, stream>>>(w_o, Wto);
  gemm_bt_kernel<true, false><<<dim3(8, 32), tb, 0, stream>>>(q_in, Wtq, Qb, 4096, 1024, 1024);
  gemm_bt_kernel<true, false><<<dim3(8, 32), tb, 0, stream>>>(k_in, Wtk, Kb, 4096, 1024, 1024);
  gemm_bt_kernel<true, false><<<dim3(8, 32), tb, 0, stream>>>(v_in, Wtv, Vb, 4096, 1024, 1024);
  attn_kernel<<<dim3(32, 32), tb, 0, stream>>>(Qb, Kb, Vb, Cb);
  gemm_bt_kernel<false, true><<<dim3(8, 32), tb, 0, stream>>>(Cb, Wto, outp, 4096, 1024, 1024);
}

// Round 2
// 198.627 us; speedup vs baseline: 1.8684x; 1.8684x over previous
//
#include <hip/hip_runtime.h>

// MHA: out = softmax_causal((XWq)(XWk)^T / 8) (XWv) Wo
// B=2 S=2048 DM=1024 H=16 d=64. Inputs fp32, output fp32, bf16 MFMA compute.

typedef __attribute__((ext_vector_type(8))) short v8s;   // 8 x bf16 (4 VGPRs)
typedef __attribute__((ext_vector_type(4))) float v4f;   // MFMA accumulator

#define MFMA16(a, b, c) __builtin_amdgcn_mfma_f32_16x16x32_bf16(a, b, c, 0, 0, 0)

#define GLOBAL_AS __attribute__((address_space(1)))
#define LDS_AS __attribute__((address_space(3)))

__device__ __forceinline__ void gload_lds16(const void* g, void* l) {
  // async global->LDS, 16B per lane; LDS dest = wave-uniform base + lane*16
  __builtin_amdgcn_global_load_lds((const GLOBAL_AS void*)g, (LDS_AS void*)l, 16, 0, 0);
}

__device__ __forceinline__ short f2bf(float f) {
  union { float f; unsigned u; } x; x.f = f;
  unsigned r = x.u + 0x7fffu + ((x.u >> 16) & 1u);  // RNE
  return (short)(r >> 16);
}

// ---------------------------------------------------------------------------
// Weight transpose+cast: W[1024][1024] f32 ([k][n]) -> Wt[n][k] bf16, z=0..3.
// z0: w_q (scale 1/8 folded), z1: w_k, z2: w_v, z3: w_o.
// Wt layout in ws: [Wto | Wtq | Wtk | Wtv] each 1M shorts.
// ---------------------------------------------------------------------------
__global__ __launch_bounds__(256) void wtrans_kernel(const float* __restrict__ w0,
                                                     const float* __restrict__ w1,
                                                     const float* __restrict__ w2,
                                                     const float* __restrict__ w3,
                                                     short* __restrict__ wtbase) {
  __shared__ __align__(16) short tile[64 * 72];
  const int NN = 1024;
  int z = blockIdx.z;
  const float* W = (z == 0) ? w0 : (z == 1) ? w1 : (z == 2) ? w2 : w3;
  short* Wt = wtbase + ((z < 3) ? ((size_t)(z + 1) << 20) : 0);
  float scale = (z == 0) ? 0.125f : 1.0f;
  int n0 = blockIdx.x * 64, k0 = blockIdx.y * 64;
  int t = threadIdx.x;
  int r = t >> 4;
  int c4 = (t & 15) * 4;
  for (int rr = r; rr < 64; rr += 16) {
    float4 f = *(const float4*)(W + (size_t)(k0 + rr) * NN + n0 + c4);
    tile[(c4 + 0) * 72 + rr] = f2bf(f.x * scale);
    tile[(c4 + 1) * 72 + rr] = f2bf(f.y * scale);
    tile[(c4 + 2) * 72 + rr] = f2bf(f.z * scale);
    tile[(c4 + 3) * 72 + rr] = f2bf(f.w * scale);
  }
  __syncthreads();
  int nr = t >> 2, kc = (t & 3) * 16;
  v8s v0 = *(const v8s*)&tile[nr * 72 + kc];
  v8s v1 = *(const v8s*)&tile[nr * 72 + kc + 8];
  *(v8s*)(Wt + (size_t)(n0 + nr) * NN + k0 + kc) = v0;
  *(v8s*)(Wt + (size_t)(n0 + nr) * NN + k0 + kc + 8) = v1;
}

// ---------------------------------------------------------------------------
// fp32 -> bf16 cast, 8 elems/thread. grid = n/(256*8).
// ---------------------------------------------------------------------------
__global__ __launch_bounds__(256) void cast_kernel(const float* __restrict__ src,
                                                   short* __restrict__ dst) {
  int i = (blockIdx.x * 256 + threadIdx.x) * 8;
  float4 f0 = *(const float4*)(src + i);
  float4 f1 = *(const float4*)(src + i + 4);
  v8s v;
  v[0] = f2bf(f0.x); v[1] = f2bf(f0.y); v[2] = f2bf(f0.z); v[3] = f2bf(f0.w);
  v[4] = f2bf(f1.x); v[5] = f2bf(f1.y); v[6] = f2bf(f1.z); v[7] = f2bf(f1.w);
  *(v8s*)(dst + i) = v;
}

// ---------------------------------------------------------------------------
// V transpose: Vb[s][h*64+d] bf16 -> Vtg[bh][d][s] bf16. grid (S/64, 32).
// ---------------------------------------------------------------------------
__global__ __launch_bounds__(256) void vtrans_kernel(const short* __restrict__ Vb,
                                                     short* __restrict__ Vtg) {
  __shared__ __align__(16) short T[64 * 72];
  const int S = 2048, DM = 1024;
  int s0 = blockIdx.x * 64;
  int bh = blockIdx.y;
  int b = bh >> 4, h = bh & 15;
  int t = threadIdx.x;
  int srow = t >> 2, sc = (t & 3) * 16;
  const short* src = Vb + (size_t)(b * S + s0 + srow) * DM + h * 64 + sc;
  v8s a = *(const v8s*)src;
  v8s c = *(const v8s*)(src + 8);
#pragma unroll
  for (int j = 0; j < 8; ++j) {
    int jj = (j + srow) & 7;  // stagger banks
    T[(sc + jj) * 72 + srow] = a[jj];
  }
#pragma unroll
  for (int j = 0; j < 8; ++j) {
    int jj = (j + srow) & 7;
    T[(sc + 8 + jj) * 72 + srow] = c[jj];
  }
  __syncthreads();
  int dr = t >> 2, oc = (t & 3) * 16;
  short* dst = Vtg + (size_t)bh * 64 * S + (size_t)dr * S + s0 + oc;
  *(v8s*)dst = *(const v8s*)&T[dr * 72 + oc];
  *(v8s*)(dst + 8) = *(const v8s*)&T[dr * 72 + oc + 8];
}

// ---------------------------------------------------------------------------
// m97-style GEMM: C[M][N] = A[M][K] * Bt[N][K]^T, all-bf16 operands,
// global_load_lds staging, linear LDS, 128x128 tile, BK=32, 4 waves.
// blockIdx.z batches independent GEMMs (A/Bt/C strided).
// ---------------------------------------------------------------------------
template <bool OUT_F32>
__global__ __launch_bounds__(256) void gemm97_kernel(
    const short* __restrict__ Ab, size_t sA,
    const short* __restrict__ Btb, size_t sB,
    short* __restrict__ Cb, float* __restrict__ Cf, size_t sC,
    int M, int N, int K) {
  __shared__ __align__(16) short As[128 * 32];
  __shared__ __align__(16) short Bs[128 * 32];
  const short* A = Ab + (size_t)blockIdx.z * sA;
  const short* Bt = Btb + (size_t)blockIdx.z * sB;
  int row0 = blockIdx.y * 128, col0 = blockIdx.x * 128;
  int t = threadIdx.x, lane = t & 63, w = t >> 6;
  int wm = (w >> 1) * 64, wn = (w & 1) * 64;
  int lr = lane & 15, lg = lane >> 4;

  v4f acc[4][4];
#pragma unroll
  for (int i = 0; i < 4; ++i)
#pragma unroll
    for (int j = 0; j < 4; ++j) acc[i][j] = {0.f, 0.f, 0.f, 0.f};

  // staging: 8 chunks of 16 rows x 32 k (1KB). wave w stages chunks {w, w+4}.
  const short* gA = A + (size_t)(row0 + w * 16 + (lane >> 2)) * K + (lane & 3) * 8;
  const short* gB = Bt + (size_t)(col0 + w * 16 + (lane >> 2)) * K + (lane & 3) * 8;
  short* lA0 = &As[w * 512];
  short* lA1 = &As[(w + 4) * 512];
  short* lB0 = &Bs[w * 512];
  short* lB1 = &Bs[(w + 4) * 512];
  const size_t rstep = (size_t)64 * K;

  for (int k0 = 0; k0 < K; k0 += 32) {
    __syncthreads();
    gload_lds16(gA + k0, lA0);
    gload_lds16(gA + rstep + k0, lA1);
    gload_lds16(gB + k0, lB0);
    gload_lds16(gB + rstep + k0, lB1);
    __syncthreads();  // compiler drains vmcnt before barrier
    v8s af[4], bg[4];
#pragma unroll
    for (int mf = 0; mf < 4; ++mf)
      af[mf] = *(const v8s*)&As[(wm + mf * 16 + lr) * 32 + lg * 8];
#pragma unroll
    for (int nf = 0; nf < 4; ++nf)
      bg[nf] = *(const v8s*)&Bs[(wn + nf * 16 + lr) * 32 + lg * 8];
#pragma unroll
    for (int mf = 0; mf < 4; ++mf)
#pragma unroll
      for (int nf = 0; nf < 4; ++nf)
        acc[mf][nf] = MFMA16(af[mf], bg[nf], acc[mf][nf]);
  }

#pragma unroll
  for (int mf = 0; mf < 4; ++mf)
#pragma unroll
    for (int nf = 0; nf < 4; ++nf)
#pragma unroll
      for (int r = 0; r < 4; ++r) {
        int row = row0 + wm + mf * 16 + lg * 4 + r;
        int col = col0 + wn + nf * 16 + lr;
        if (OUT_F32)
          (Cf + (size_t)blockIdx.z * sC)[(size_t)row * N + col] = acc[mf][nf][r];
        else
          (Cb + (size_t)blockIdx.z * sC)[(size_t)row * N + col] = f2bf(acc[mf][nf][r]);
      }
}

// ---------------------------------------------------------------------------
// Causal flash attention, swapped-QK^T softmax.
// Q/K bf16 [b*S+s][h*64+d]; V pre-transposed Vtg[bh][d][s]; out Cm like Q.
// Block = (qt, bh): 64 q rows, 4 waves x 16 rows. KT=64 keys/iter.
// Per-lane softmax state is for q = lane&15 (replicated over lane>>4).
// ---------------------------------------------------------------------------
__global__ __launch_bounds__(256) void attn_kernel(const short* __restrict__ Qm,
                                                   const short* __restrict__ Km,
                                                   const short* __restrict__ Vt_g,
                                                   short* __restrict__ Cm) {
  const int S = 2048, DM = 1024;
  __shared__ __align__(16) short Ks[64 * 64];    // [k][d] linear (global_load_lds)
  __shared__ __align__(16) short Vs[64 * 64];    // [d][k] linear (global_load_lds)
  __shared__ __align__(16) short Pt[4][16 * 72]; // per-wave P[q][k], stride 72

  int qt = gridDim.x - 1 - blockIdx.x;  // long blocks first (tail packing)
  int bh = blockIdx.y;
  int b = bh >> 4, h = bh & 15;
  int t = threadIdx.x, lane = t & 63, w = t >> 6;
  int lr = lane & 15, lg = lane >> 4;
  size_t base = (size_t)b * S * DM + h * 64;
  size_t vbase = (size_t)bh * 64 * S;
  int qbase = qt * 64 + w * 16;
  int qg = qbase + lr;

  // Q fragments (B-operand rows, indexed by lr), scale folded into Wq
  const short* Qp = Qm + base + (size_t)(qbase + lr) * DM + lg * 8;
  v8s qf0 = *(const v8s*)Qp;
  v8s qf1 = *(const v8s*)(Qp + 32);

  // staging base addrs (8-row chunks, wave w stages chunks {w, w+4})
  const short* gK = Km + base + (size_t)(w * 8 + (lane >> 3)) * DM + (lane & 7) * 8;
  const short* gV = Vt_g + vbase + (size_t)(w * 8 + (lane >> 3)) * S + (lane & 7) * 8;

  float mrow = -1e30f, ssum = 0.f;
  v4f o[4];
#pragma unroll
  for (int d4 = 0; d4 < 4; ++d4) o[d4] = {0.f, 0.f, 0.f, 0.f};

  int nkt = qt + 1;
  for (int kt = 0; kt < nkt; ++kt) {
    int k0 = kt * 64;
    __syncthreads();  // previous iter's LDS reads done
    gload_lds16(gK + (size_t)k0 * DM, &Ks[w * 512]);
    gload_lds16(gK + (size_t)(k0 + 32) * DM, &Ks[(w + 4) * 512]);
    gload_lds16(gV + k0, &Vs[w * 512]);
    gload_lds16(gV + 32 * S + k0, &Vs[(w + 4) * 512]);
    __syncthreads();  // vmcnt drained before barrier -> tiles ready

    // S^T tiles: st[t2][r] = S[q=lr][k0 + t2*16 + lg*4 + r]
    v4f st[4];
#pragma unroll
    for (int t2 = 0; t2 < 4; ++t2) {
      v4f s = {0.f, 0.f, 0.f, 0.f};
      v8s a0 = *(const v8s*)&Ks[(t2 * 16 + lr) * 64 + lg * 8];
      v8s a1 = *(const v8s*)&Ks[(t2 * 16 + lr) * 64 + 32 + lg * 8];
      s = MFMA16(a0, qf0, s);
      s = MFMA16(a1, qf1, s);
      st[t2] = s;
    }

    if (kt == nkt - 1) {  // causal mask (only last tile can violate)
#pragma unroll
      for (int t2 = 0; t2 < 4; ++t2)
#pragma unroll
        for (int r = 0; r < 4; ++r)
          if (k0 + t2 * 16 + lg * 4 + r > qg) st[t2][r] = -1e30f;
    }

    // row max: 15 in-lane fmax + 2 shuffles
    float tm = -1e30f;
#pragma unroll
    for (int t2 = 0; t2 < 4; ++t2)
#pragma unroll
      for (int r = 0; r < 4; ++r) tm = fmaxf(tm, st[t2][r]);
    tm = fmaxf(tm, __shfl_xor(tm, 16, 64));
    tm = fmaxf(tm, __shfl_xor(tm, 32, 64));

    float nm = fmaxf(mrow, tm);
    float scl = __expf(mrow - nm);
    mrow = nm;
    float p[4][4];
    float ts = 0.f;
#pragma unroll
    for (int t2 = 0; t2 < 4; ++t2)
#pragma unroll
      for (int r = 0; r < 4; ++r) {
        p[t2][r] = __expf(st[t2][r] - nm);
        ts += p[t2][r];
      }
    ts += __shfl_xor(ts, 16, 64);
    ts += __shfl_xor(ts, 32, 64);
    ssum = ssum * scl + ts;

    // rescale O (rows q = lg*4+r need that row's scl, held at lane lg*4+r)
    float sclo[4];
#pragma unroll
    for (int r = 0; r < 4; ++r) sclo[r] = __shfl(scl, lg * 4 + r, 64);
#pragma unroll
    for (int d4 = 0; d4 < 4; ++d4)
#pragma unroll
      for (int r = 0; r < 4; ++r) o[d4][r] *= sclo[r];

    // P -> wave-private LDS (bf16, packed b64 writes)
#pragma unroll
    for (int t2 = 0; t2 < 4; ++t2) {
      unsigned lo = ((unsigned)(unsigned short)f2bf(p[t2][1]) << 16) |
                    (unsigned short)f2bf(p[t2][0]);
      unsigned hi = ((unsigned)(unsigned short)f2bf(p[t2][3]) << 16) |
                    (unsigned short)f2bf(p[t2][2]);
      uint2 u; u.x = lo; u.y = hi;
      *(uint2*)&Pt[w][lr * 72 + t2 * 16 + lg * 4] = u;
    }

    // PV: A = P rows (q=lr), B = Vt rows (d=lr); D rows q = lg*4+r
    v8s pa0 = *(const v8s*)&Pt[w][lr * 72 + lg * 8];
    v8s pa1 = *(const v8s*)&Pt[w][lr * 72 + 32 + lg * 8];
#pragma unroll
    for (int d4 = 0; d4 < 4; ++d4) {
      v8s v0 = *(const v8s*)&Vs[(d4 * 16 + lr) * 64 + lg * 8];
      v8s v1 = *(const v8s*)&Vs[(d4 * 16 + lr) * 64 + 32 + lg * 8];
      o[d4] = MFMA16(pa0, v0, o[d4]);
      o[d4] = MFMA16(pa1, v1, o[d4]);
    }
  }

  float sv[4];
#pragma unroll
  for (int r = 0; r < 4; ++r) sv[r] = 1.0f / __shfl(ssum, lg * 4 + r, 64);
  short* Cp = Cm + base;
#pragma unroll
  for (int r = 0; r < 4; ++r)
#pragma unroll
    for (int d4 = 0; d4 < 4; ++d4)
      Cp[(size_t)(qbase + lg * 4 + r) * DM + d4 * 16 + lr] = f2bf(o[d4][r] * sv[r]);
}

// ---------------------------------------------------------------------------
extern "C" void kernel_launch(void* const* d_in, const int* in_sizes, int n_in,
                              void* d_out, int out_size, void* d_ws, size_t ws_size,
                              hipStream_t stream) {
  const float* q_in = (const float*)d_in[0];
  const float* k_in = (const float*)d_in[1];
  const float* v_in = (const float*)d_in[2];
  // d_in[3] = mask: causal triu(k=1), applied analytically in attn_kernel
  const float* w_q = (const float*)d_in[4];
  const float* w_k = (const float*)d_in[5];
  const float* w_v = (const float*)d_in[6];
  const float* w_o = (const float*)d_in[7];
  float* outp = (float*)d_out;

  short* ws = (short*)d_ws;
  const size_t M1 = (size_t)1 << 20;  // 1M shorts = 2MB
  short* Wto = ws;                    // [0:1M)
  short* Wtq = ws + 1 * M1;           // Wtq/Wtk/Wtv contiguous for z-batch
  dim3 tb(256);

  wtrans_kernel<<<dim3(16, 16, 4), tb, 0, stream>>>(w_q, w_k, w_v, w_o, ws);

  bool big = ws_size >= ((size_t)56 << 20);
  if (big) {
    // [Wt 0:4M][X3 4M:16M][Qb 16M][Kb 20M][Vb 24M:28M); Vtg<-4M, Cb<-8M
    short* X = ws + 4 * M1;
    short* Qb = ws + 16 * M1;
    short* Vb = ws + 24 * M1;
    short* Vtg = ws + 4 * M1;
    short* Cb = ws + 8 * M1;
    cast_kernel<<<dim3(2048), tb, 0, stream>>>(q_in, X);
    cast_kernel<<<dim3(2048), tb, 0, stream>>>(k_in, X + 4 * M1);
    cast_kernel<<<dim3(2048), tb, 0, stream>>>(v_in, X + 8 * M1);
    gemm97_kernel<false><<<dim3(8, 32, 3), tb, 0, stream>>>(
        X, 4 * M1, Wtq, M1, Qb, nullptr, 4 * M1, 4096, 1024, 1024);
    vtrans_kernel<<<dim3(32, 32), tb, 0, stream>>>(Vb, Vtg);
    attn_kernel<<<dim3(32, 32), tb, 0, stream>>>(Qb, ws + 20 * M1, Vtg, Cb);
    gemm97_kernel<true><<<dim3(8, 32, 1), tb, 0, stream>>>(
        Cb, 0, Wto, 0, nullptr, outp, 0, 4096, 1024, 1024);
  } else {
    // 40MB fallback: [Wt 0:4M][X 4M:8M][Qb 8M][Kb 12M][Vb 16M:20M)
    // Vtg <- 1M:5M (Wtq..X, dead), Cb <- Vb (dead after vtrans)
    short* X = ws + 4 * M1;
    short* Qb = ws + 8 * M1;
    short* Kb = ws + 12 * M1;
    short* Vb = ws + 16 * M1;
    short* Vtg = ws + 1 * M1;
    short* Cb = Vb;
    cast_kernel<<<dim3(2048), tb, 0, stream>>>(q_in, X);
    gemm97_kernel<false><<<dim3(8, 32, 1), tb, 0, stream>>>(
        X, 0, Wtq, 0, Qb, nullptr, 0, 4096, 1024, 1024);
    cast_kernel<<<dim3(2048), tb, 0, stream>>>(k_in, X);
    gemm97_kernel<false><<<dim3(8, 32, 1), tb, 0, stream>>>(
        X, 0, Wtq + M1, 0, Kb, nullptr, 0, 4096, 1024, 1024);
    cast_kernel<<<dim3(2048), tb, 0, stream>>>(v_in, X);
    gemm97_kernel<false><<<dim3(8, 32, 1), tb, 0, stream>>>(
        X, 0, Wtq + 2 * M1, 0, Vb, nullptr, 0, 4096, 1024, 1024);
    vtrans_kernel<<<dim3(32, 32), tb, 0, stream>>>(Vb, Vtg);
    attn_kernel<<<dim3(32, 32), tb, 0, stream>>>(Qb, Kb, Vtg, Cb);
    gemm97_kernel<true><<<dim3(8, 32, 1), tb, 0, stream>>>(
        Cb, 0, Wto, 0, nullptr, outp, 0, 4096, 1024, 1024);
  }
}

// Round 3
// 148.988 us; speedup vs baseline: 2.4909x; 1.3332x over previous
//
#include <hip/hip_runtime.h>

// MHA: out = softmax_causal((XWq)(XWk)^T / 8) (XWv) Wo
// B=2 S=2048 DM=1024 H=16 d=64. Inputs fp32, output fp32, bf16 MFMA compute.

typedef __attribute__((ext_vector_type(8))) short v8s;   // 8 x bf16 (4 VGPRs)
typedef __attribute__((ext_vector_type(4))) float v4f;   // MFMA accumulator

#define MFMA16(a, b, c) __builtin_amdgcn_mfma_f32_16x16x32_bf16(a, b, c, 0, 0, 0)

#define GLOBAL_AS __attribute__((address_space(1)))
#define LDS_AS __attribute__((address_space(3)))

__device__ __forceinline__ void gload_lds16(const void* g, void* l) {
  // async global->LDS, 16B per lane; LDS dest = wave-uniform base + lane*16
  __builtin_amdgcn_global_load_lds((const GLOBAL_AS void*)g, (LDS_AS void*)l, 16, 0, 0);
}

__device__ __forceinline__ short f2bf(float f) {
  union { float f; unsigned u; } x; x.f = f;
  unsigned r = x.u + 0x7fffu + ((x.u >> 16) & 1u);  // RNE
  return (short)(r >> 16);
}

// ---------------------------------------------------------------------------
// Weight transpose+cast: W[1024][1024] f32 ([k][n]) -> Wt[n][k] bf16, z=0..3.
// z0: w_q (scale 1/8 folded), z1: w_k, z2: w_v, z3: w_o.
// Wt layout in ws: [Wto | Wtq | Wtk | Wtv] each 1M shorts.
// ---------------------------------------------------------------------------
__global__ __launch_bounds__(256) void wtrans_kernel(const float* __restrict__ w0,
                                                     const float* __restrict__ w1,
                                                     const float* __restrict__ w2,
                                                     const float* __restrict__ w3,
                                                     short* __restrict__ wtbase) {
  __shared__ __align__(16) short tile[64 * 72];
  const int NN = 1024;
  int z = blockIdx.z;
  const float* W = (z == 0) ? w0 : (z == 1) ? w1 : (z == 2) ? w2 : w3;
  short* Wt = wtbase + ((z < 3) ? ((size_t)(z + 1) << 20) : 0);
  float scale = (z == 0) ? 0.125f : 1.0f;
  int n0 = blockIdx.x * 64, k0 = blockIdx.y * 64;
  int t = threadIdx.x;
  int r = t >> 4;
  int c4 = (t & 15) * 4;
  for (int rr = r; rr < 64; rr += 16) {
    float4 f = *(const float4*)(W + (size_t)(k0 + rr) * NN + n0 + c4);
    tile[(c4 + 0) * 72 + rr] = f2bf(f.x * scale);
    tile[(c4 + 1) * 72 + rr] = f2bf(f.y * scale);
    tile[(c4 + 2) * 72 + rr] = f2bf(f.z * scale);
    tile[(c4 + 3) * 72 + rr] = f2bf(f.w * scale);
  }
  __syncthreads();
  int nr = t >> 2, kc = (t & 3) * 16;
  v8s v0 = *(const v8s*)&tile[nr * 72 + kc];
  v8s v1 = *(const v8s*)&tile[nr * 72 + kc + 8];
  *(v8s*)(Wt + (size_t)(n0 + nr) * NN + k0 + kc) = v0;
  *(v8s*)(Wt + (size_t)(n0 + nr) * NN + k0 + kc + 8) = v1;
}

// ---------------------------------------------------------------------------
// fp32 -> bf16 cast, 8 elems/thread. grid = n/(256*8).
// ---------------------------------------------------------------------------
__global__ __launch_bounds__(256) void cast_kernel(const float* __restrict__ src,
                                                   short* __restrict__ dst) {
  int i = (blockIdx.x * 256 + threadIdx.x) * 8;
  float4 f0 = *(const float4*)(src + i);
  float4 f1 = *(const float4*)(src + i + 4);
  v8s v;
  v[0] = f2bf(f0.x); v[1] = f2bf(f0.y); v[2] = f2bf(f0.z); v[3] = f2bf(f0.w);
  v[4] = f2bf(f1.x); v[5] = f2bf(f1.y); v[6] = f2bf(f1.z); v[7] = f2bf(f1.w);
  *(v8s*)(dst + i) = v;
}

// ---------------------------------------------------------------------------
// V transpose: Vb[s][h*64+d] bf16 -> Vtg[bh][d][s] bf16. grid (S/64, 32).
// ---------------------------------------------------------------------------
__global__ __launch_bounds__(256) void vtrans_kernel(const short* __restrict__ Vb,
                                                     short* __restrict__ Vtg) {
  __shared__ __align__(16) short T[64 * 72];
  const int S = 2048, DM = 1024;
  int s0 = blockIdx.x * 64;
  int bh = blockIdx.y;
  int b = bh >> 4, h = bh & 15;
  int t = threadIdx.x;
  int srow = t >> 2, sc = (t & 3) * 16;
  const short* src = Vb + (size_t)(b * S + s0 + srow) * DM + h * 64 + sc;
  v8s a = *(const v8s*)src;
  v8s c = *(const v8s*)(src + 8);
#pragma unroll
  for (int j = 0; j < 8; ++j) {
    int jj = (j + srow) & 7;  // stagger banks
    T[(sc + jj) * 72 + srow] = a[jj];
  }
#pragma unroll
  for (int j = 0; j < 8; ++j) {
    int jj = (j + srow) & 7;
    T[(sc + 8 + jj) * 72 + srow] = c[jj];
  }
  __syncthreads();
  int dr = t >> 2, oc = (t & 3) * 16;
  short* dst = Vtg + (size_t)bh * 64 * S + (size_t)dr * S + s0 + oc;
  *(v8s*)dst = *(const v8s*)&T[dr * 72 + oc];
  *(v8s*)(dst + 8) = *(const v8s*)&T[dr * 72 + oc + 8];
}

// ---------------------------------------------------------------------------
// m97-style GEMM, 2-phase double-buffered, XOR-swizzled LDS (T2 via
// pre-swizzled global source, rule #21): C = A[M][K] * Bt[N][K]^T, bf16.
// 128x128 tile, BK=32, 4 waves. blockIdx.z batches independent GEMMs.
// Tile rows are 64B = 4 16B-slots; s(row) = (row ^ (row>>2)) & 3 gives
// conflict-free 8-lane service groups (distinct (bit6,slot) pairs).
// ---------------------------------------------------------------------------
template <bool OUT_F32>
__global__ __launch_bounds__(256) void gemm97_kernel(
    const short* __restrict__ Ab, size_t sA,
    const short* __restrict__ Btb, size_t sB,
    short* __restrict__ Cb, float* __restrict__ Cf, size_t sC,
    int M, int N, int K) {
  __shared__ __align__(16) short As[2][128 * 32];
  __shared__ __align__(16) short Bs[2][128 * 32];
  const short* A = Ab + (size_t)blockIdx.z * sA;
  const short* Bt = Btb + (size_t)blockIdx.z * sB;
  int row0 = blockIdx.y * 128, col0 = blockIdx.x * 128;
  int t = threadIdx.x, lane = t & 63, w = t >> 6;
  int wm = (w >> 1) * 64, wn = (w & 1) * 64;
  int lr = lane & 15, lg = lane >> 4;

  v4f acc[4][4];
#pragma unroll
  for (int i = 0; i < 4; ++i)
#pragma unroll
    for (int j = 0; j < 4; ++j) acc[i][j] = {0.f, 0.f, 0.f, 0.f};

  // staging: 1KB chunks of 16 rows x 32k; wave w stages chunks {w, w+4}.
  // lane l -> phys row l>>2, slot l&3; source col slot = (l&3) ^ s(row).
  int rl = lane >> 2, sl = lane & 3;
  int scol = ((sl ^ (rl ^ (rl >> 2))) & 3) * 8;
  const short* gA = A + (size_t)(row0 + w * 16 + rl) * K + scol;
  const short* gB = Bt + (size_t)(col0 + w * 16 + rl) * K + scol;
  const size_t rstep = (size_t)64 * K;

#define GEMM_STAGE(buf, k0_)                              \
  do {                                                    \
    gload_lds16(gA + (k0_), &As[buf][w * 512]);           \
    gload_lds16(gA + rstep + (k0_), &As[buf][(w + 4) * 512]); \
    gload_lds16(gB + (k0_), &Bs[buf][w * 512]);           \
    gload_lds16(gB + rstep + (k0_), &Bs[buf][(w + 4) * 512]); \
  } while (0)

  GEMM_STAGE(0, 0);
  __syncthreads();
  int cur = 0;
  int rsw = (lr ^ (lr >> 2)) & 3;  // read swizzle: rr&3=lr&3, (rr>>2)&3≡(lr>>2)&3
  for (int k0 = 0; k0 < K; k0 += 32) {
    if (k0 + 32 < K) GEMM_STAGE(cur ^ 1, k0 + 32);
    v8s af[4], bg[4];
#pragma unroll
    for (int mf = 0; mf < 4; ++mf)
      af[mf] = *(const v8s*)&As[cur][(wm + mf * 16 + lr) * 32 + ((lg ^ rsw) * 8)];
#pragma unroll
    for (int nf = 0; nf < 4; ++nf)
      bg[nf] = *(const v8s*)&Bs[cur][(wn + nf * 16 + lr) * 32 + ((lg ^ rsw) * 8)];
#pragma unroll
    for (int mf = 0; mf < 4; ++mf)
#pragma unroll
      for (int nf = 0; nf < 4; ++nf)
        acc[mf][nf] = MFMA16(af[mf], bg[nf], acc[mf][nf]);
    __syncthreads();  // drains prefetch vmcnt + all LDS reads; 1 barrier/iter
    cur ^= 1;
  }
#undef GEMM_STAGE

#pragma unroll
  for (int mf = 0; mf < 4; ++mf)
#pragma unroll
    for (int nf = 0; nf < 4; ++nf)
#pragma unroll
      for (int r = 0; r < 4; ++r) {
        int row = row0 + wm + mf * 16 + lg * 4 + r;
        int col = col0 + wn + nf * 16 + lr;
        if (OUT_F32)
          (Cf + (size_t)blockIdx.z * sC)[(size_t)row * N + col] = acc[mf][nf][r];
        else
          (Cb + (size_t)blockIdx.z * sC)[(size_t)row * N + col] = f2bf(acc[mf][nf][r]);
      }
}

// ---------------------------------------------------------------------------
// Causal flash attention, swapped-QK^T softmax, 2-phase double-buffer,
// XOR-swizzled K/V LDS. Block bx in [0,16) processes q-tiles {bx, 31-bx}
// (33 K-tile iters each -> perfect load balance, 512 blocks = 2/CU).
// K/V tiles [64][64 shorts=128B]: 8 slots/row, s(row) = row&7.
// ---------------------------------------------------------------------------
__global__ __launch_bounds__(256) void attn_kernel(const short* __restrict__ Qm,
                                                   const short* __restrict__ Km,
                                                   const short* __restrict__ Vt_g,
                                                   short* __restrict__ Cm) {
  const int S = 2048, DM = 1024;
  __shared__ __align__(16) short Ks[2][64 * 64];
  __shared__ __align__(16) short Vs[2][64 * 64];
  __shared__ __align__(16) short Pt[4][16 * 72];  // per-wave P[q][k], stride 72

  int bx = blockIdx.x;  // 0..15
  int bh = blockIdx.y;
  int b = bh >> 4, h = bh & 15;
  int t = threadIdx.x, lane = t & 63, w = t >> 6;
  int lr = lane & 15, lg = lane >> 4;
  size_t base = (size_t)b * S * DM + h * 64;
  size_t vbase = (size_t)bh * 64 * S;

  // staging: 1KB chunks of 8 rows x 128B; wave w stages chunks {w, w+4}.
  // lane l -> phys row l>>3, slot l&7; source col slot = (l&7) ^ (row&7).
  int srow = w * 8 + (lane >> 3);
  int scol = ((lane & 7) ^ (lane >> 3)) * 8;
  const short* gK = Km + base + (size_t)srow * DM + scol;
  const short* gV = Vt_g + vbase + (size_t)srow * S + scol;
  int sw = (lr & 7) * 8;  // read swizzle (rr&7 == lr&7 for 16-aligned tiles)

#define ATTN_STAGE(buf, kt_)                                                  \
  do {                                                                        \
    size_t k0_ = (size_t)(kt_) * 64;                                          \
    gload_lds16(gK + k0_ * DM, &Ks[buf][w * 512]);                            \
    gload_lds16(gK + (k0_ + 32) * DM, &Ks[buf][(w + 4) * 512]);               \
    gload_lds16(gV + k0_, &Vs[buf][w * 512]);                                 \
    gload_lds16(gV + (size_t)32 * S + k0_, &Vs[buf][(w + 4) * 512]);          \
  } while (0)

#pragma unroll 1
  for (int qsel = 0; qsel < 2; ++qsel) {
    int qt = qsel ? (31 - bx) : bx;
    int qbase = qt * 64 + w * 16;
    int qg = qbase + lr;
    int nkt = qt + 1;

    // Q fragments (B-operand rows, indexed by lr); 1/8 scale folded into Wq
    const short* Qp = Qm + base + (size_t)(qbase + lr) * DM + lg * 8;
    v8s qf0 = *(const v8s*)Qp;
    v8s qf1 = *(const v8s*)(Qp + 32);

    float mrow = -1e30f, ssum = 0.f;
    v4f o[4];
#pragma unroll
    for (int d4 = 0; d4 < 4; ++d4) o[d4] = {0.f, 0.f, 0.f, 0.f};

    ATTN_STAGE(0, 0);
    __syncthreads();
    int cur = 0;
    for (int kt = 0; kt < nkt; ++kt) {
      int k0 = kt * 64;
      if (kt + 1 < nkt) ATTN_STAGE(cur ^ 1, kt + 1);

      // S^T tiles: st[t2][r] = S[q=lr][k0 + t2*16 + lg*4 + r]
      v4f st[4];
#pragma unroll
      for (int t2 = 0; t2 < 4; ++t2) {
        v4f s = {0.f, 0.f, 0.f, 0.f};
        v8s a0 = *(const v8s*)&Ks[cur][(t2 * 16 + lr) * 64 + ((lg * 8) ^ sw)];
        v8s a1 = *(const v8s*)&Ks[cur][(t2 * 16 + lr) * 64 + ((32 + lg * 8) ^ sw)];
        s = MFMA16(a0, qf0, s);
        s = MFMA16(a1, qf1, s);
        st[t2] = s;
      }

      if (kt == nkt - 1) {  // causal mask (only last tile can violate)
#pragma unroll
        for (int t2 = 0; t2 < 4; ++t2)
#pragma unroll
          for (int r = 0; r < 4; ++r)
            if (k0 + t2 * 16 + lg * 4 + r > qg) st[t2][r] = -1e30f;
      }

      // row max: 15 in-lane fmax + 2 shuffles
      float tm = -1e30f;
#pragma unroll
      for (int t2 = 0; t2 < 4; ++t2)
#pragma unroll
        for (int r = 0; r < 4; ++r) tm = fmaxf(tm, st[t2][r]);
      tm = fmaxf(tm, __shfl_xor(tm, 16, 64));
      tm = fmaxf(tm, __shfl_xor(tm, 32, 64));

      float nm = fmaxf(mrow, tm);
      float scl = __expf(mrow - nm);
      mrow = nm;
      float p[4][4];
      float ts = 0.f;
#pragma unroll
      for (int t2 = 0; t2 < 4; ++t2)
#pragma unroll
        for (int r = 0; r < 4; ++r) {
          p[t2][r] = __expf(st[t2][r] - nm);
          ts += p[t2][r];
        }
      ts += __shfl_xor(ts, 16, 64);
      ts += __shfl_xor(ts, 32, 64);
      ssum = ssum * scl + ts;

      // rescale O (rows q = lg*4+r need that row's scl, held at lane lg*4+r)
      float sclo[4];
#pragma unroll
      for (int r = 0; r < 4; ++r) sclo[r] = __shfl(scl, lg * 4 + r, 64);
#pragma unroll
      for (int d4 = 0; d4 < 4; ++d4)
#pragma unroll
        for (int r = 0; r < 4; ++r) o[d4][r] *= sclo[r];

      // P -> wave-private LDS (bf16, packed b64 writes)
#pragma unroll
      for (int t2 = 0; t2 < 4; ++t2) {
        unsigned lo = ((unsigned)(unsigned short)f2bf(p[t2][1]) << 16) |
                      (unsigned short)f2bf(p[t2][0]);
        unsigned hi = ((unsigned)(unsigned short)f2bf(p[t2][3]) << 16) |
                      (unsigned short)f2bf(p[t2][2]);
        uint2 u; u.x = lo; u.y = hi;
        *(uint2*)&Pt[w][lr * 72 + t2 * 16 + lg * 4] = u;
      }

      // PV: A = P rows (q=lr), B = Vt rows (d=lr); D rows q = lg*4+r
      v8s pa0 = *(const v8s*)&Pt[w][lr * 72 + lg * 8];
      v8s pa1 = *(const v8s*)&Pt[w][lr * 72 + 32 + lg * 8];
#pragma unroll
      for (int d4 = 0; d4 < 4; ++d4) {
        v8s v0 = *(const v8s*)&Vs[cur][(d4 * 16 + lr) * 64 + ((lg * 8) ^ sw)];
        v8s v1 = *(const v8s*)&Vs[cur][(d4 * 16 + lr) * 64 + ((32 + lg * 8) ^ sw)];
        o[d4] = MFMA16(pa0, v0, o[d4]);
        o[d4] = MFMA16(pa1, v1, o[d4]);
      }
      __syncthreads();  // drains prefetch vmcnt + LDS reads; 1 barrier/iter
      cur ^= 1;
    }

    float sv[4];
#pragma unroll
    for (int r = 0; r < 4; ++r) sv[r] = 1.0f / __shfl(ssum, lg * 4 + r, 64);
    short* Cp = Cm + base;
#pragma unroll
    for (int r = 0; r < 4; ++r)
#pragma unroll
      for (int d4 = 0; d4 < 4; ++d4)
        Cp[(size_t)(qbase + lg * 4 + r) * DM + d4 * 16 + lr] = f2bf(o[d4][r] * sv[r]);
  }
#undef ATTN_STAGE
}

// ---------------------------------------------------------------------------
extern "C" void kernel_launch(void* const* d_in, const int* in_sizes, int n_in,
                              void* d_out, int out_size, void* d_ws, size_t ws_size,
                              hipStream_t stream) {
  const float* q_in = (const float*)d_in[0];
  const float* k_in = (const float*)d_in[1];
  const float* v_in = (const float*)d_in[2];
  // d_in[3] = mask: causal triu(k=1), applied analytically in attn_kernel
  const float* w_q = (const float*)d_in[4];
  const float* w_k = (const float*)d_in[5];
  const float* w_v = (const float*)d_in[6];
  const float* w_o = (const float*)d_in[7];
  float* outp = (float*)d_out;

  short* ws = (short*)d_ws;
  const size_t M1 = (size_t)1 << 20;  // 1M shorts = 2MB
  short* Wto = ws;                    // [0:1M)
  short* Wtq = ws + 1 * M1;           // Wtq/Wtk/Wtv contiguous for z-batch
  dim3 tb(256);

  wtrans_kernel<<<dim3(16, 16, 4), tb, 0, stream>>>(w_q, w_k, w_v, w_o, ws);

  bool big = ws_size >= ((size_t)56 << 20);
  if (big) {
    // [Wt 0:4M][X3 4M:16M][Qb 16M][Kb 20M][Vb 24M:28M); Vtg<-4M, Cb<-8M
    short* X = ws + 4 * M1;
    short* Qb = ws + 16 * M1;
    short* Vb = ws + 24 * M1;
    short* Vtg = ws + 4 * M1;
    short* Cb = ws + 8 * M1;
    cast_kernel<<<dim3(2048), tb, 0, stream>>>(q_in, X);
    cast_kernel<<<dim3(2048), tb, 0, stream>>>(k_in, X + 4 * M1);
    cast_kernel<<<dim3(2048), tb, 0, stream>>>(v_in, X + 8 * M1);
    gemm97_kernel<false><<<dim3(8, 32, 3), tb, 0, stream>>>(
        X, 4 * M1, Wtq, M1, Qb, nullptr, 4 * M1, 4096, 1024, 1024);
    vtrans_kernel<<<dim3(32, 32), tb, 0, stream>>>(Vb, Vtg);
    attn_kernel<<<dim3(16, 32), tb, 0, stream>>>(Qb, ws + 20 * M1, Vtg, Cb);
    gemm97_kernel<true><<<dim3(8, 32, 1), tb, 0, stream>>>(
        Cb, 0, Wto, 0, nullptr, outp, 0, 4096, 1024, 1024);
  } else {
    // 40MB fallback: [Wt 0:4M][X 4M:8M][Qb 8M][Kb 12M][Vb 16M:20M)
    // Vtg <- 1M:5M (Wtq..X, dead), Cb <- Vb (dead after vtrans)
    short* X = ws + 4 * M1;
    short* Qb = ws + 8 * M1;
    short* Kb = ws + 12 * M1;
    short* Vb = ws + 16 * M1;
    short* Vtg = ws + 1 * M1;
    short* Cb = Vb;
    cast_kernel<<<dim3(2048), tb, 0, stream>>>(q_in, X);
    gemm97_kernel<false><<<dim3(8, 32, 1), tb, 0, stream>>>(
        X, 0, Wtq, 0, Qb, nullptr, 0, 4096, 1024, 1024);
    cast_kernel<<<dim3(2048), tb, 0, stream>>>(k_in, X);
    gemm97_kernel<false><<<dim3(8, 32, 1), tb, 0, stream>>>(
        X, 0, Wtq + M1, 0, Kb, nullptr, 0, 4096, 1024, 1024);
    cast_kernel<<<dim3(2048), tb, 0, stream>>>(v_in, X);
    gemm97_kernel<false><<<dim3(8, 32, 1), tb, 0, stream>>>(
        X, 0, Wtq + 2 * M1, 0, Vb, nullptr, 0, 4096, 1024, 1024);
    vtrans_kernel<<<dim3(32, 32), tb, 0, stream>>>(Vb, Vtg);
    attn_kernel<<<dim3(16, 32), tb, 0, stream>>>(Qb, Kb, Vtg, Cb);
    gemm97_kernel<true><<<dim3(8, 32, 1), tb, 0, stream>>>(
        Cb, 0, Wto, 0, nullptr, outp, 0, 4096, 1024, 1024);
  }
}